// Round 1
// baseline (587.692 us; speedup 1.0000x reference)
//
#include <hip/hip_runtime.h>

typedef unsigned short u16;
typedef __bf16 bf16x8 __attribute__((ext_vector_type(8)));
typedef float f32x4 __attribute__((ext_vector_type(4)));

// ---------- helpers ----------
__device__ __forceinline__ u16 f2bf(float f) {
  unsigned u = __float_as_uint(f);
  unsigned r = u + 0x7fffu + ((u >> 16) & 1u);   // RNE
  return (u16)(r >> 16);
}

__device__ __forceinline__ void async_cp16(const void* g, void* l) {
  // global -> LDS direct, 16B per lane. LDS dst is wave-uniform base + lane*16.
  __builtin_amdgcn_global_load_lds((__attribute__((address_space(1))) void*)g,
                                   (__attribute__((address_space(3))) void*)l,
                                   16, 0, 0);
}

// ---------- fused LayerNorm + bf16 cast ----------
// one block per row of 1024
__global__ __launch_bounds__(256)
void ln_cast(const float* __restrict__ X, const float* __restrict__ W,
             const float* __restrict__ Bv, u16* __restrict__ Y) {
  __shared__ float red[8];
  const int row = blockIdx.x, t = threadIdx.x;
  const int wave = t >> 6, lane = t & 63;
  const float4 v = ((const float4*)(X + (size_t)row * 1024))[t];
  float s  = v.x + v.y + v.z + v.w;
  float ss = v.x*v.x + v.y*v.y + v.z*v.z + v.w*v.w;
#pragma unroll
  for (int m = 32; m; m >>= 1) { s += __shfl_xor(s, m, 64); ss += __shfl_xor(ss, m, 64); }
  if (lane == 0) { red[wave] = s; red[4 + wave] = ss; }
  __syncthreads();
  float S  = red[0] + red[1] + red[2] + red[3];
  float SS = red[4] + red[5] + red[6] + red[7];
  float mu  = S * (1.0f / 1024.0f);
  float var = SS * (1.0f / 1024.0f) - mu * mu;
  float rstd = rsqrtf(var + 1e-5f);
  const float4 wv = ((const float4*)W)[t];
  const float4 bv = ((const float4*)Bv)[t];
  ushort4 o;
  o.x = f2bf((v.x - mu) * rstd * wv.x + bv.x);
  o.y = f2bf((v.y - mu) * rstd * wv.y + bv.y);
  o.z = f2bf((v.z - mu) * rstd * wv.z + bv.z);
  o.w = f2bf((v.w - mu) * rstd * wv.w + bv.w);
  ((ushort4*)(Y + (size_t)row * 1024))[t] = o;
}

// ---------- weight transpose + cast: W[K=1024][N=1024] f32 -> WT[N][K] bf16 ----------
__global__ __launch_bounds__(256)
void wtrans(const float* __restrict__ W, u16* __restrict__ WT) {
  __shared__ float t[64][65];
  const int k0 = blockIdx.y * 64, n0 = blockIdx.x * 64;
  const int lr = threadIdx.x >> 4, lc = threadIdx.x & 15;
#pragma unroll
  for (int r = 0; r < 4; ++r) {
    int row = r * 16 + lr;
    float4 v = *(const float4*)(W + (size_t)(k0 + row) * 1024 + n0 + lc * 4);
    t[row][lc*4+0] = v.x; t[row][lc*4+1] = v.y; t[row][lc*4+2] = v.z; t[row][lc*4+3] = v.w;
  }
  __syncthreads();
#pragma unroll
  for (int r = 0; r < 4; ++r) {
    int n = r * 16 + lr;
    ushort4 o;
    o.x = f2bf(t[lc*4+0][n]); o.y = f2bf(t[lc*4+1][n]);
    o.z = f2bf(t[lc*4+2][n]); o.w = f2bf(t[lc*4+3][n]);
    *(ushort4*)(WT + (size_t)(n0 + n) * 1024 + k0 + lc * 4) = o;
  }
}

// ---------- V transpose: V[b][kk][h][d] f32 -> VT[b][h][d][kk] bf16 ----------
__global__ __launch_bounds__(256)
void vtrans(const float* __restrict__ V, u16* __restrict__ VT) {
  __shared__ float t[64][65];
  const int b = blockIdx.z, h = blockIdx.y, kk0 = blockIdx.x * 64;
  const int lr = threadIdx.x >> 4, lc = threadIdx.x & 15;
#pragma unroll
  for (int r = 0; r < 4; ++r) {
    int row = r * 16 + lr;  // kk within tile
    float4 v = *(const float4*)(V + (size_t)(b * 2048 + kk0 + row) * 1024 + h * 64 + lc * 4);
    t[row][lc*4+0] = v.x; t[row][lc*4+1] = v.y; t[row][lc*4+2] = v.z; t[row][lc*4+3] = v.w;
  }
  __syncthreads();
#pragma unroll
  for (int r = 0; r < 4; ++r) {
    int d = r * 16 + lr;
    ushort4 o;
    o.x = f2bf(t[lc*4+0][d]); o.y = f2bf(t[lc*4+1][d]);
    o.z = f2bf(t[lc*4+2][d]); o.w = f2bf(t[lc*4+3][d]);
    *(ushort4*)(VT + ((size_t)(b * 16 + h) * 64 + d) * 2048 + kk0 + lc * 4) = o;
  }
}

// ---------- per-64-segment l2 norm + cast ----------
__global__ __launch_bounds__(256)
void l2norm_cast(const float* __restrict__ X, u16* __restrict__ Y) {
  const size_t seg = (size_t)blockIdx.x * 4 + (threadIdx.x >> 6);
  const int lane = threadIdx.x & 63;
  const size_t idx = seg * 64 + lane;
  float v = X[idx];
  float ss = v * v;
#pragma unroll
  for (int m = 32; m; m >>= 1) ss += __shfl_xor(ss, m, 64);
  float n = sqrtf(ss);
  float sc = 1.0f / fmaxf(n, 1e-12f);
  Y[idx] = f2bf(v * sc);
}

// ---------- GEMM: C[M][N] f32 = A[M][K] bf16 x BT[N][K] bf16 (m97 structure) ----------
__global__ __launch_bounds__(256, 2)
void gemm_bt(const u16* __restrict__ A, const u16* __restrict__ Bt,
             float* __restrict__ C, int M, int N, int K) {
  __shared__ __align__(16) u16 As[128 * 64];
  __shared__ __align__(16) u16 Bs[128 * 64];
  const int tid = threadIdx.x;
  const int wave = tid >> 6, lane = tid & 63;
  const int quad = lane >> 4, l15 = lane & 15;
  const int m0 = blockIdx.y * 128, n0 = blockIdx.x * 128;
  const int wm = (wave >> 1) * 64, wn = (wave & 1) * 64;
  const int srow = lane >> 3, scol = (lane & 7) * 8;

  const f32x4 fz = {0.f, 0.f, 0.f, 0.f};
  f32x4 acc[4][4];
#pragma unroll
  for (int i = 0; i < 4; ++i)
#pragma unroll
    for (int j = 0; j < 4; ++j) acc[i][j] = fz;

  for (int kt = 0; kt < K; kt += 64) {
    __syncthreads();
#pragma unroll
    for (int r = 0; r < 4; ++r) {
      const int c = r * 4 + wave;
      const int row = c * 8 + srow;
      async_cp16(A  + (size_t)(m0 + row) * K + kt + scol, (char*)As + c * 1024);
      async_cp16(Bt + (size_t)(n0 + row) * K + kt + scol, (char*)Bs + c * 1024);
    }
    __syncthreads();
#pragma unroll
    for (int ks = 0; ks < 2; ++ks) {
      bf16x8 af[4], bfr[4];
#pragma unroll
      for (int i = 0; i < 4; ++i)
        af[i] = *(const bf16x8*)(const void*)(As + (wm + i * 16 + l15) * 64 + ks * 32 + quad * 8);
#pragma unroll
      for (int j = 0; j < 4; ++j)
        bfr[j] = *(const bf16x8*)(const void*)(Bs + (wn + j * 16 + l15) * 64 + ks * 32 + quad * 8);
#pragma unroll
      for (int i = 0; i < 4; ++i)
#pragma unroll
        for (int j = 0; j < 4; ++j)
          acc[i][j] = __builtin_amdgcn_mfma_f32_16x16x32_bf16(af[i], bfr[j], acc[i][j], 0, 0, 0);
    }
  }
#pragma unroll
  for (int i = 0; i < 4; ++i)
#pragma unroll
    for (int j = 0; j < 4; ++j)
#pragma unroll
      for (int e = 0; e < 4; ++e) {
        int row = m0 + wm + i * 16 + quad * 4 + e;
        int col = n0 + wn + j * 16 + l15;
        C[(size_t)row * N + col] = acc[i][j][e];
      }
}

// ---------- flash attention: grid (Lq/64, H, B), block 256 ----------
__global__ __launch_bounds__(256, 2)
void flash_attn(const u16* __restrict__ Qb, const u16* __restrict__ Kb,
                const u16* __restrict__ Vt, const int* __restrict__ mask,
                const float* __restrict__ taup, u16* __restrict__ Ob) {
  __shared__ __align__(16) u16 Qs[64 * 64];
  __shared__ __align__(16) u16 Ks[64 * 64];
  __shared__ __align__(16) u16 Vs[64 * 64];   // VT tile: [d][kk]
  __shared__ __align__(16) u16 Ps[64 * 64];   // [q][kk], wave-private 16-row strips
  const int tid = threadIdx.x, wave = tid >> 6, lane = tid & 63;
  const int quad = lane >> 4, l15 = lane & 15;
  const int b = blockIdx.z, h = blockIdx.y, q0 = blockIdx.x * 64;
  const float scale = 1.0f / (taup[0] + 1e-6f);
  const int srow = lane >> 3, scol = (lane & 7) * 8;

  // stage Q tile [64 q][64 d]
#pragma unroll
  for (int r = 0; r < 2; ++r) {
    int c = r * 4 + wave;
    int row = c * 8 + srow;
    async_cp16(Qb + (size_t)(b * 2048 + q0 + row) * 1024 + h * 64 + scol, (char*)Qs + c * 1024);
  }
  __syncthreads();
  bf16x8 aq[2];
  aq[0] = *(const bf16x8*)(const void*)(Qs + (wave * 16 + l15) * 64 + quad * 8);
  aq[1] = *(const bf16x8*)(const void*)(Qs + (wave * 16 + l15) * 64 + 32 + quad * 8);

  const f32x4 fz = {0.f, 0.f, 0.f, 0.f};
  f32x4 o[4];
#pragma unroll
  for (int j = 0; j < 4; ++j) o[j] = fz;
  float mrow[4] = {-INFINITY, -INFINITY, -INFINITY, -INFINITY};
  float lrow[4] = {0.f, 0.f, 0.f, 0.f};

  for (int kt = 0; kt < 2048; kt += 64) {
    __syncthreads();
#pragma unroll
    for (int r = 0; r < 2; ++r) {
      int c = r * 4 + wave;
      int row = c * 8 + srow;
      async_cp16(Kb + (size_t)(b * 2048 + kt + row) * 1024 + h * 64 + scol, (char*)Ks + c * 1024);
      async_cp16(Vt + ((size_t)(b * 16 + h) * 64 + row) * 2048 + kt + scol, (char*)Vs + c * 1024);
    }
    __syncthreads();

    // S[q][kk] = Q . K^T  (K natural [kk][d] layout == BT operand)
    f32x4 s[4];
#pragma unroll
    for (int j = 0; j < 4; ++j) {
      bf16x8 b0 = *(const bf16x8*)(const void*)(Ks + (j * 16 + l15) * 64 + quad * 8);
      bf16x8 b1 = *(const bf16x8*)(const void*)(Ks + (j * 16 + l15) * 64 + 32 + quad * 8);
      f32x4 z = fz;
      z = __builtin_amdgcn_mfma_f32_16x16x32_bf16(aq[0], b0, z, 0, 0, 0);
      z = __builtin_amdgcn_mfma_f32_16x16x32_bf16(aq[1], b1, z, 0, 0, 0);
      s[j] = z;
    }
    // scale + mask (valid |s| <= ~8.1, sentinel far below)
#pragma unroll
    for (int j = 0; j < 4; ++j) {
      int kcol = kt + j * 16 + l15;
      bool mk = mask[b * 2048 + kcol] != 0;
#pragma unroll
      for (int e = 0; e < 4; ++e)
        s[j][e] = mk ? -30000.0f : s[j][e] * scale;
    }
    // online softmax update (rows grouped by (quad,e), reduce across l15)
#pragma unroll
    for (int e = 0; e < 4; ++e) {
      float v = fmaxf(fmaxf(s[0][e], s[1][e]), fmaxf(s[2][e], s[3][e]));
      v = fmaxf(v, __shfl_xor(v, 1, 64));
      v = fmaxf(v, __shfl_xor(v, 2, 64));
      v = fmaxf(v, __shfl_xor(v, 4, 64));
      v = fmaxf(v, __shfl_xor(v, 8, 64));
      float mnew = fmaxf(mrow[e], v);
      float alpha = __expf(mrow[e] - mnew);
      mrow[e] = mnew;
      lrow[e] *= alpha;
#pragma unroll
      for (int j = 0; j < 4; ++j) o[j][e] *= alpha;
    }
    // P = exp(s - m) -> LDS (C-layout write), row sums
    float rs[4] = {0.f, 0.f, 0.f, 0.f};
#pragma unroll
    for (int j = 0; j < 4; ++j)
#pragma unroll
      for (int e = 0; e < 4; ++e) {
        float p = __expf(s[j][e] - mrow[e]);
        rs[e] += p;
        Ps[(wave * 16 + quad * 4 + e) * 64 + j * 16 + l15] = f2bf(p);
      }
#pragma unroll
    for (int e = 0; e < 4; ++e) {
      float v = rs[e];
      v += __shfl_xor(v, 1, 64); v += __shfl_xor(v, 2, 64);
      v += __shfl_xor(v, 4, 64); v += __shfl_xor(v, 8, 64);
      lrow[e] += v;
    }
    // O += P @ V  (P re-read in A-layout; V^T tile gives contiguous B-frag)
#pragma unroll
    for (int ks = 0; ks < 2; ++ks) {
      bf16x8 pa = *(const bf16x8*)(const void*)(Ps + (wave * 16 + l15) * 64 + ks * 32 + quad * 8);
#pragma unroll
      for (int j = 0; j < 4; ++j) {
        bf16x8 vb = *(const bf16x8*)(const void*)(Vs + (j * 16 + l15) * 64 + ks * 32 + quad * 8);
        o[j] = __builtin_amdgcn_mfma_f32_16x16x32_bf16(pa, vb, o[j], 0, 0, 0);
      }
    }
  }
  // epilogue: O / l -> bf16
#pragma unroll
  for (int e = 0; e < 4; ++e) {
    float inv = 1.0f / lrow[e];
    int q = q0 + wave * 16 + quad * 4 + e;
#pragma unroll
    for (int j = 0; j < 4; ++j) {
      int d = j * 16 + l15;
      Ob[(size_t)(b * 2048 + q) * 1024 + h * 64 + d] = f2bf(o[j][e] * inv);
    }
  }
}

// ---------- launch ----------
extern "C" void kernel_launch(void* const* d_in, const int* in_sizes, int n_in,
                              void* d_out, int out_size, void* d_ws, size_t ws_size,
                              hipStream_t stream) {
  const float* x    = (const float*)d_in[0];
  const float* ctx  = (const float*)d_in[1];
  const int*   mask = (const int*)d_in[2];
  const float* lnqw = (const float*)d_in[3];
  const float* lnqb = (const float*)d_in[4];
  const float* lncw = (const float*)d_in[5];
  const float* lncb = (const float*)d_in[6];
  const float* Wq   = (const float*)d_in[7];
  const float* Wk   = (const float*)d_in[8];
  const float* Wv   = (const float*)d_in[9];
  const float* Wo   = (const float*)d_in[10];
  const float* tau  = (const float*)d_in[11];
  float* out = (float*)d_out;
  char* ws = (char*)d_ws;
  const size_t MB = 1024 * 1024;

  u16* qin  = (u16*)(ws + 0 * MB);    // 16 MB; reused as attn-out later
  u16* kvin = (u16*)(ws + 16 * MB);   // 16 MB
  u16* WqT  = (u16*)(ws + 32 * MB);   // 2 MB each
  u16* WkT  = (u16*)(ws + 34 * MB);
  u16* WvT  = (u16*)(ws + 36 * MB);
  u16* WoT  = (u16*)(ws + 38 * MB);
  u16* qbf  = (u16*)(ws + 40 * MB);   // 16 MB
  u16* kbf  = (u16*)(ws + 56 * MB);   // 16 MB
  u16* vT   = (u16*)(ws + 72 * MB);   // 16 MB  (total 88 MB)
  float* scr = out;                   // d_out (32 MB f32) as projection scratch
  u16* attn = qin;                    // qin dead after first GEMM

  ln_cast<<<8192, 256, 0, stream>>>(x,   lnqw, lnqb, qin);
  ln_cast<<<8192, 256, 0, stream>>>(ctx, lncw, lncb, kvin);
  wtrans<<<dim3(16, 16), 256, 0, stream>>>(Wq, WqT);
  wtrans<<<dim3(16, 16), 256, 0, stream>>>(Wk, WkT);
  wtrans<<<dim3(16, 16), 256, 0, stream>>>(Wv, WvT);
  wtrans<<<dim3(16, 16), 256, 0, stream>>>(Wo, WoT);

  gemm_bt<<<dim3(8, 64), 256, 0, stream>>>(qin, WqT, scr, 8192, 1024, 1024);
  l2norm_cast<<<32768, 256, 0, stream>>>(scr, qbf);

  gemm_bt<<<dim3(8, 64), 256, 0, stream>>>(kvin, WkT, scr, 8192, 1024, 1024);
  l2norm_cast<<<32768, 256, 0, stream>>>(scr, kbf);

  gemm_bt<<<dim3(8, 64), 256, 0, stream>>>(kvin, WvT, scr, 8192, 1024, 1024);
  vtrans<<<dim3(32, 16, 4), 256, 0, stream>>>(scr, vT);

  flash_attn<<<dim3(32, 16, 4), 256, 0, stream>>>(qbf, kbf, vT, mask, tau, attn);

  gemm_bt<<<dim3(8, 64), 256, 0, stream>>>(attn, WoT, out, 8192, 1024, 1024);
}

// Round 3
// 459.765 us; speedup vs baseline: 1.2782x; 1.2782x over previous
//
#include <hip/hip_runtime.h>

typedef unsigned short u16;
typedef __bf16 bf16x8 __attribute__((ext_vector_type(8)));
typedef float f32x4 __attribute__((ext_vector_type(4)));

// ---------- helpers ----------
__device__ __forceinline__ u16 f2bf(float f) {
  unsigned u = __float_as_uint(f);
  unsigned r = u + 0x7fffu + ((u >> 16) & 1u);   // RNE
  return (u16)(r >> 16);
}

__device__ __forceinline__ void async_cp16(const void* g, void* l) {
  // global -> LDS direct, 16B per lane. LDS dst is wave-uniform base + lane*16.
  __builtin_amdgcn_global_load_lds((__attribute__((address_space(1))) void*)g,
                                   (__attribute__((address_space(3))) void*)l,
                                   16, 0, 0);
}

// ---------- fused LayerNorm + bf16 cast ----------
__global__ __launch_bounds__(256)
void ln_cast(const float* __restrict__ X, const float* __restrict__ W,
             const float* __restrict__ Bv, u16* __restrict__ Y) {
  __shared__ float red[8];
  const int row = blockIdx.x, t = threadIdx.x;
  const int wave = t >> 6, lane = t & 63;
  const float4 v = ((const float4*)(X + (size_t)row * 1024))[t];
  float s  = v.x + v.y + v.z + v.w;
  float ss = v.x*v.x + v.y*v.y + v.z*v.z + v.w*v.w;
#pragma unroll
  for (int m = 32; m; m >>= 1) { s += __shfl_xor(s, m, 64); ss += __shfl_xor(ss, m, 64); }
  if (lane == 0) { red[wave] = s; red[4 + wave] = ss; }
  __syncthreads();
  float S  = red[0] + red[1] + red[2] + red[3];
  float SS = red[4] + red[5] + red[6] + red[7];
  float mu  = S * (1.0f / 1024.0f);
  float var = SS * (1.0f / 1024.0f) - mu * mu;
  float rstd = rsqrtf(var + 1e-5f);
  const float4 wv = ((const float4*)W)[t];
  const float4 bv = ((const float4*)Bv)[t];
  ushort4 o;
  o.x = f2bf((v.x - mu) * rstd * wv.x + bv.x);
  o.y = f2bf((v.y - mu) * rstd * wv.y + bv.y);
  o.z = f2bf((v.z - mu) * rstd * wv.z + bv.z);
  o.w = f2bf((v.w - mu) * rstd * wv.w + bv.w);
  ((ushort4*)(Y + (size_t)row * 1024))[t] = o;
}

// ---------- weight transpose + cast: W[K][N] f32 -> WT[N][K] bf16 ----------
__global__ __launch_bounds__(256)
void wtrans(const float* __restrict__ W, u16* __restrict__ WT) {
  __shared__ float t[64][65];
  const int k0 = blockIdx.y * 64, n0 = blockIdx.x * 64;
  const int lr = threadIdx.x >> 4, lc = threadIdx.x & 15;
#pragma unroll
  for (int r = 0; r < 4; ++r) {
    int row = r * 16 + lr;
    float4 v = *(const float4*)(W + (size_t)(k0 + row) * 1024 + n0 + lc * 4);
    t[row][lc*4+0] = v.x; t[row][lc*4+1] = v.y; t[row][lc*4+2] = v.z; t[row][lc*4+3] = v.w;
  }
  __syncthreads();
#pragma unroll
  for (int r = 0; r < 4; ++r) {
    int n = r * 16 + lr;
    ushort4 o;
    o.x = f2bf(t[lc*4+0][n]); o.y = f2bf(t[lc*4+1][n]);
    o.z = f2bf(t[lc*4+2][n]); o.w = f2bf(t[lc*4+3][n]);
    *(ushort4*)(WT + (size_t)(n0 + n) * 1024 + k0 + lc * 4) = o;
  }
}

// ---------- V transpose: V[b][kk][h][d] f32 -> VT[b][h][d][kk] bf16 ----------
__global__ __launch_bounds__(256)
void vtrans(const float* __restrict__ V, u16* __restrict__ VT) {
  __shared__ float t[64][65];
  const int b = blockIdx.z, h = blockIdx.y, kk0 = blockIdx.x * 64;
  const int lr = threadIdx.x >> 4, lc = threadIdx.x & 15;
#pragma unroll
  for (int r = 0; r < 4; ++r) {
    int row = r * 16 + lr;
    float4 v = *(const float4*)(V + (size_t)(b * 2048 + kk0 + row) * 1024 + h * 64 + lc * 4);
    t[row][lc*4+0] = v.x; t[row][lc*4+1] = v.y; t[row][lc*4+2] = v.z; t[row][lc*4+3] = v.w;
  }
  __syncthreads();
#pragma unroll
  for (int r = 0; r < 4; ++r) {
    int d = r * 16 + lr;
    ushort4 o;
    o.x = f2bf(t[lc*4+0][d]); o.y = f2bf(t[lc*4+1][d]);
    o.z = f2bf(t[lc*4+2][d]); o.w = f2bf(t[lc*4+3][d]);
    *(ushort4*)(VT + ((size_t)(b * 16 + h) * 64 + d) * 2048 + kk0 + lc * 4) = o;
  }
}

// ---------- per-64-segment l2 norm + cast; optionally folds softmax scale*log2e into q ----------
__global__ __launch_bounds__(256)
void l2norm_cast(const float* __restrict__ X, u16* __restrict__ Y,
                 const float* __restrict__ taup, int scaled) {
  const size_t seg = (size_t)blockIdx.x * 4 + (threadIdx.x >> 6);
  const int lane = threadIdx.x & 63;
  const size_t idx = seg * 64 + lane;
  float v = X[idx];
  float ss = v * v;
#pragma unroll
  for (int m = 32; m; m >>= 1) ss += __shfl_xor(ss, m, 64);
  float n = sqrtf(ss);
  float sc = 1.0f / fmaxf(n, 1e-12f);
  if (scaled) sc *= 1.44269504f / (taup[0] + 1e-6f);  // fold 1/(tau+eps) * log2(e)
  Y[idx] = f2bf(v * sc);
}

// ---------- GEMM: C[M][N] f32 = A[M][K] bf16 x BT[N][K] bf16 (m97 structure) ----------
__global__ __launch_bounds__(256, 2)
void gemm_bt(const u16* __restrict__ A, const u16* __restrict__ Bt,
             float* __restrict__ C, int M, int N, int K) {
  __shared__ __align__(16) u16 As[128 * 64];
  __shared__ __align__(16) u16 Bs[128 * 64];
  const int tid = threadIdx.x;
  const int wave = tid >> 6, lane = tid & 63;
  const int quad = lane >> 4, l15 = lane & 15;
  const int m0 = blockIdx.y * 128, n0 = blockIdx.x * 128;
  const int wm = (wave >> 1) * 64, wn = (wave & 1) * 64;
  const int srow = lane >> 3, scol = (lane & 7) * 8;

  const f32x4 fz = {0.f, 0.f, 0.f, 0.f};
  f32x4 acc[4][4];
#pragma unroll
  for (int i = 0; i < 4; ++i)
#pragma unroll
    for (int j = 0; j < 4; ++j) acc[i][j] = fz;

  for (int kt = 0; kt < K; kt += 64) {
    __syncthreads();
#pragma unroll
    for (int r = 0; r < 4; ++r) {
      const int c = r * 4 + wave;
      const int row = c * 8 + srow;
      async_cp16(A  + (size_t)(m0 + row) * K + kt + scol, (char*)As + c * 1024);
      async_cp16(Bt + (size_t)(n0 + row) * K + kt + scol, (char*)Bs + c * 1024);
    }
    __syncthreads();
#pragma unroll
    for (int ks = 0; ks < 2; ++ks) {
      bf16x8 af[4], bfr[4];
#pragma unroll
      for (int i = 0; i < 4; ++i)
        af[i] = *(const bf16x8*)(const void*)(As + (wm + i * 16 + l15) * 64 + ks * 32 + quad * 8);
#pragma unroll
      for (int j = 0; j < 4; ++j)
        bfr[j] = *(const bf16x8*)(const void*)(Bs + (wn + j * 16 + l15) * 64 + ks * 32 + quad * 8);
#pragma unroll
      for (int i = 0; i < 4; ++i)
#pragma unroll
        for (int j = 0; j < 4; ++j)
          acc[i][j] = __builtin_amdgcn_mfma_f32_16x16x32_bf16(af[i], bfr[j], acc[i][j], 0, 0, 0);
    }
  }
#pragma unroll
  for (int i = 0; i < 4; ++i)
#pragma unroll
    for (int j = 0; j < 4; ++j)
#pragma unroll
      for (int e = 0; e < 4; ++e) {
        int row = m0 + wm + i * 16 + quad * 4 + e;
        int col = n0 + wn + j * 16 + l15;
        C[(size_t)row * N + col] = acc[i][j][e];
      }
}

// ---------- flash attention v2: 256q/block, 64q/wave, no online softmax ----------
// q is pre-scaled by log2e/(tau+eps); p = exp2(S) * maskmul; row-sum reduced once at end.
// Mask is staged as raw ints into LDS (no global float buffer -> stays in proven ws footprint).
__global__ __launch_bounds__(256, 2)
void flash_attn2(const u16* __restrict__ Qb, const u16* __restrict__ Kb,
                 const u16* __restrict__ Vt, const int* __restrict__ mask,
                 u16* __restrict__ Ob) {
  __shared__ __align__(16) u16 QPs[256 * 64];   // Q staging, then P scratch (swizzled)
  __shared__ __align__(16) u16 Ks[64 * 64];
  __shared__ __align__(16) u16 Vs[64 * 64];     // VT tile [d][kk]
  __shared__ __align__(16) int Mshi[2048];
  const int tid = threadIdx.x, w = tid >> 6, lane = tid & 63;
  const int quad = lane >> 4, l15 = lane & 15;
  const int b = blockIdx.z, h = blockIdx.y, q0 = blockIdx.x * 256;
  const int srow = lane >> 3, scol = (lane & 7) * 8;

  // stage Q tile (256x64) + mask ints (2048)
#pragma unroll
  for (int r = 0; r < 8; ++r) {
    int c = w * 8 + r;
    async_cp16(Qb + (size_t)(b * 2048 + q0 + c * 8 + srow) * 1024 + h * 64 + scol,
               (char*)QPs + c * 1024);
  }
#pragma unroll
  for (int r = 0; r < 2; ++r) {
    int c = w * 2 + r;
    async_cp16(mask + b * 2048 + c * 256 + lane * 4, (char*)Mshi + c * 1024);
  }
  __syncthreads();

  // Q fragments live in registers for the whole kernel (wave's own 64 rows)
  bf16x8 aq[4][2];
#pragma unroll
  for (int i = 0; i < 4; ++i)
#pragma unroll
    for (int ks = 0; ks < 2; ++ks)
      aq[i][ks] = *(const bf16x8*)(const void*)(QPs + (w * 64 + i * 16 + l15) * 64 + ks * 32 + quad * 8);

  // precomputed swizzled P addresses (write: C-layout rows; read: A-layout rows)
  // swizzle: column byte bits 5-6 XOR'd with (row>>2)&3  -> conflict-free b16 scatter
  u16* wp[4];
#pragma unroll
  for (int j = 0; j < 4; ++j)
    wp[j] = (u16*)((char*)QPs + ((w * 64 + quad * 4) << 7) + (l15 << 1) + ((j ^ quad) << 5));
  const int g = l15 >> 2;
  const char* rp[2];
#pragma unroll
  for (int ks = 0; ks < 2; ++ks)
    rp[ks] = (char*)QPs + ((w * 64 + l15) << 7)
           + ((quad & 1) << 4) + ((((quad >> 1) ^ (g & 1))) << 5) + (((ks ^ (g >> 1))) << 6);

  const f32x4 fz = {0.f, 0.f, 0.f, 0.f};
  f32x4 o[4][4], rs[4];
#pragma unroll
  for (int i = 0; i < 4; ++i) {
    rs[i] = fz;
#pragma unroll
    for (int j = 0; j < 4; ++j) o[i][j] = fz;
  }

  for (int kt = 0; kt < 2048; kt += 64) {
    __syncthreads();
#pragma unroll
    for (int r = 0; r < 2; ++r) {
      int c = w * 2 + r;
      async_cp16(Kb + (size_t)(b * 2048 + kt + c * 8 + srow) * 1024 + h * 64 + scol,
                 (char*)Ks + c * 1024);
      async_cp16(Vt + ((size_t)(b * 16 + h) * 64 + c * 8 + srow) * 2048 + kt + scol,
                 (char*)Vs + c * 1024);
    }
    __syncthreads();

    float mm[4];
#pragma unroll
    for (int j = 0; j < 4; ++j) mm[j] = Mshi[kt + j * 16 + l15] ? 0.0f : 1.0f;
    bf16x8 kb[4][2];
#pragma unroll
    for (int j = 0; j < 4; ++j)
#pragma unroll
      for (int ks = 0; ks < 2; ++ks)
        kb[j][ks] = *(const bf16x8*)(const void*)(Ks + (j * 16 + l15) * 64 + ks * 32 + quad * 8);

    // S = Q.K^T (already includes softmax scale via q); p = exp2(S)*mm -> P scratch
#pragma unroll
    for (int i = 0; i < 4; ++i) {
#pragma unroll
      for (int j = 0; j < 4; ++j) {
        f32x4 s = fz;
        s = __builtin_amdgcn_mfma_f32_16x16x32_bf16(aq[i][0], kb[j][0], s, 0, 0, 0);
        s = __builtin_amdgcn_mfma_f32_16x16x32_bf16(aq[i][1], kb[j][1], s, 0, 0, 0);
#pragma unroll
        for (int e = 0; e < 4; ++e) {
          float p = exp2f(s[e]) * mm[j];
          rs[i][e] += p;
          unsigned u = __float_as_uint(p) + 0x8000u;   // round-half-up to bf16
          wp[j][i * 1024 + e * 64] = (u16)(u >> 16);
        }
      }
    }

    // O += P @ V  (P reload in A-layout via swizzled b128; V^T tile -> contiguous B-frag)
#pragma unroll
    for (int ks = 0; ks < 2; ++ks) {
      bf16x8 vb[4], pa[4];
#pragma unroll
      for (int j = 0; j < 4; ++j)
        vb[j] = *(const bf16x8*)(const void*)(Vs + (j * 16 + l15) * 64 + ks * 32 + quad * 8);
#pragma unroll
      for (int i = 0; i < 4; ++i)
        pa[i] = *(const bf16x8*)(const void*)(rp[ks] + i * 2048);
#pragma unroll
      for (int i = 0; i < 4; ++i)
#pragma unroll
        for (int j = 0; j < 4; ++j)
          o[i][j] = __builtin_amdgcn_mfma_f32_16x16x32_bf16(pa[i], vb[j], o[i][j], 0, 0, 0);
    }
  }

  // epilogue: single row-sum reduction across the 16 l15 lanes, then normalize+store
#pragma unroll
  for (int i = 0; i < 4; ++i) {
    f32x4 r = rs[i];
#pragma unroll
    for (int e = 0; e < 4; ++e) {
      float v = r[e];
      v += __shfl_xor(v, 1, 64); v += __shfl_xor(v, 2, 64);
      v += __shfl_xor(v, 4, 64); v += __shfl_xor(v, 8, 64);
      float inv = 1.0f / v;
      int q = q0 + w * 64 + i * 16 + quad * 4 + e;
#pragma unroll
      for (int j = 0; j < 4; ++j)
        Ob[(size_t)(b * 2048 + q) * 1024 + h * 64 + j * 16 + l15] = f2bf(o[i][j][e] * inv);
    }
  }
}

// ---------- launch ----------
extern "C" void kernel_launch(void* const* d_in, const int* in_sizes, int n_in,
                              void* d_out, int out_size, void* d_ws, size_t ws_size,
                              hipStream_t stream) {
  const float* x    = (const float*)d_in[0];
  const float* ctx  = (const float*)d_in[1];
  const int*   mask = (const int*)d_in[2];
  const float* lnqw = (const float*)d_in[3];
  const float* lnqb = (const float*)d_in[4];
  const float* lncw = (const float*)d_in[5];
  const float* lncb = (const float*)d_in[6];
  const float* Wq   = (const float*)d_in[7];
  const float* Wk   = (const float*)d_in[8];
  const float* Wv   = (const float*)d_in[9];
  const float* Wo   = (const float*)d_in[10];
  const float* tau  = (const float*)d_in[11];
  float* out = (float*)d_out;
  char* ws = (char*)d_ws;
  const size_t MB = 1024 * 1024;

  u16* qin  = (u16*)(ws + 0 * MB);    // 16 MB; reused as attn-out later
  u16* kvin = (u16*)(ws + 16 * MB);   // 16 MB
  u16* WqT  = (u16*)(ws + 32 * MB);   // 2 MB each
  u16* WkT  = (u16*)(ws + 34 * MB);
  u16* WvT  = (u16*)(ws + 36 * MB);
  u16* WoT  = (u16*)(ws + 38 * MB);
  u16* qbf  = (u16*)(ws + 40 * MB);   // 16 MB
  u16* kbf  = (u16*)(ws + 56 * MB);   // 16 MB
  u16* vT   = (u16*)(ws + 72 * MB);   // 16 MB  (total 88 MB — proven footprint)
  float* scr = out;                   // d_out (32 MB f32) as projection scratch
  u16* attn = qin;                    // qin dead after first GEMM

  ln_cast<<<8192, 256, 0, stream>>>(x,   lnqw, lnqb, qin);
  ln_cast<<<8192, 256, 0, stream>>>(ctx, lncw, lncb, kvin);
  wtrans<<<dim3(16, 16), 256, 0, stream>>>(Wq, WqT);
  wtrans<<<dim3(16, 16), 256, 0, stream>>>(Wk, WkT);
  wtrans<<<dim3(16, 16), 256, 0, stream>>>(Wv, WvT);
  wtrans<<<dim3(16, 16), 256, 0, stream>>>(Wo, WoT);

  gemm_bt<<<dim3(8, 64), 256, 0, stream>>>(qin, WqT, scr, 8192, 1024, 1024);
  l2norm_cast<<<32768, 256, 0, stream>>>(scr, qbf, tau, 1);

  gemm_bt<<<dim3(8, 64), 256, 0, stream>>>(kvin, WkT, scr, 8192, 1024, 1024);
  l2norm_cast<<<32768, 256, 0, stream>>>(scr, kbf, tau, 0);

  gemm_bt<<<dim3(8, 64), 256, 0, stream>>>(kvin, WvT, scr, 8192, 1024, 1024);
  vtrans<<<dim3(32, 16, 4), 256, 0, stream>>>(scr, vT);

  flash_attn2<<<dim3(8, 16, 4), 256, 0, stream>>>(qbf, kbf, vT, mask, attn);

  gemm_bt<<<dim3(8, 64), 256, 0, stream>>>(attn, WoT, out, 8192, 1024, 1024);
}